// Round 4
// baseline (77.232 us; speedup 1.0000x reference)
//
#include <hip/hip_runtime.h>
#include <math.h>

// Problem constants
#define NB 2
#define HIMG 96
#define HO 65
#define NCROPS (NB*HO*HO)   // 8450

// pool1: [cls3=(img,o1,o2)][16ch][46][46]
#define P1_PLANE (46*46)          // 2116
#define P1_SIZE (8*16*P1_PLANE)   // 270848
// conv2: [cls3][32ch][44][44]
#define C2_PLANE (44*44)          // 1936
#define C2_SIZE (8*32*C2_PLANE)   // 495616
// pool2: [cls5=(img,o1,o2,p1,p2)][32ch][22][22]
#define P2_PLANE (22*22)          // 484
#define P2_SIZE (32*32*P2_PLANE)  // 495616

typedef __attribute__((ext_vector_type(8))) short bf16x8;
typedef __attribute__((ext_vector_type(4))) float f32x4;

__device__ __forceinline__ unsigned int f2bf(float x) {
    unsigned int u = __builtin_bit_cast(unsigned int, x);
    return (u + 0x7fffu + ((u >> 16) & 1u)) >> 16;
}

// Merged front kernel:
//   blocks [0,529)   : conv1(5x5,1->16)+ReLU+2x2 maxpool at parity -> pool1
//   blocks [529,601) : cast fc1_w -> bf16 wB
//   blocks [601,673) : zero heatmap
__global__ void k_front(const float* __restrict__ x, const float* __restrict__ w1,
                        const float* __restrict__ b1, float* __restrict__ pool1,
                        const float* __restrict__ fc1_w, unsigned short* __restrict__ wB,
                        float* __restrict__ out) {
    int b = blockIdx.x, tid = threadIdx.x;
    if (b >= 529) {
        if (b < 601) {
            int t = (b - 529) * 256 + tid;            // < 18432, 8 elements each
            const float4* src = (const float4*)fc1_w + t * 2;
            float4 a = src[0], c = src[1];
            uint4 v;
            v.x = f2bf(a.x) | (f2bf(a.y) << 16);
            v.y = f2bf(a.z) | (f2bf(a.w) << 16);
            v.z = f2bf(c.x) | (f2bf(c.y) << 16);
            v.w = f2bf(c.z) | (f2bf(c.w) << 16);
            ((uint4*)wB)[t] = v;
        } else {
            out[(b - 601) * 256 + tid] = 0.f;
        }
        return;
    }
    int idx = b * 256 + tid;                          // < 135424
    int pg = idx % 23;
    int t  = idx / 23;
    int py = t % 46;  t /= 46;
    int ch = t % 16;  t /= 16;                        // t = cls3
    int o2 = t & 1, o1 = (t >> 1) & 1, img = t >> 2;
    const float* xim = x + img * (HIMG * HIMG);

    int rbase = 2 * py + o1;
    int cbase = 4 * pg + o2;
    float a[6][8];
    #pragma unroll
    for (int i = 0; i < 6; ++i) {
        int r = rbase + i; if (r > 95) r = 95;
        const float* rp = xim + r * 96;
        #pragma unroll
        for (int j = 0; j < 8; ++j) {
            int c = cbase + j; if (c > 95) c = 95;
            a[i][j] = rp[c];
        }
    }
    const float* wc = w1 + ch * 25;
    float w[25];
    #pragma unroll
    for (int u = 0; u < 25; ++u) w[u] = wc[u];
    float bias = b1[ch];

    float out0 = 0.f, out1 = 0.f;   // relu'd values >= 0
    #pragma unroll
    for (int dy = 0; dy < 2; ++dy)
        #pragma unroll
        for (int dx = 0; dx < 2; ++dx) {
            float s0 = bias, s1 = bias;
            #pragma unroll
            for (int ky = 0; ky < 5; ++ky)
                #pragma unroll
                for (int kx = 0; kx < 5; ++kx) {
                    float wv = w[ky * 5 + kx];
                    s0 += a[dy + ky][dx + kx] * wv;
                    s1 += a[dy + ky][2 + dx + kx] * wv;
                }
            out0 = fmaxf(out0, s0);
            out1 = fmaxf(out1, s1);
        }
    int base = ((t * 16 + ch) * 46 + py) * 46 + 2 * pg;
    float2 v; v.x = out0; v.y = out1;
    *(float2*)&pool1[base] = v;
}

// conv2(3x3,16->32)+ReLU; 4 outputs along x per thread, float4 store.
__global__ void k_conv2(const float* __restrict__ pool1, const float* __restrict__ w2,
                        const float* __restrict__ b2, float* __restrict__ conv2) {
    int idx = blockIdx.x * 256 + threadIdx.x;     // < 123904
    int og = idx % 11;
    int t  = idx / 11;
    int oy = t % 44;  t /= 44;
    int oc = t % 32;  t /= 32;                    // t = cls3
    int ox0 = og * 4;
    const float* p1 = pool1 + t * 16 * P1_PLANE + oy * 46 + ox0;
    const float* ww = w2 + oc * 144;
    float b = b2[oc];
    float s0 = b, s1 = b, s2 = b, s3 = b;
    for (int ic = 0; ic < 16; ++ic) {
        const float* pp = p1 + ic * P1_PLANE;
        const float* wk = ww + ic * 9;
        #pragma unroll
        for (int ky = 0; ky < 3; ++ky) {
            const float* r = pp + ky * 46;
            float w0 = wk[ky * 3], w1v = wk[ky * 3 + 1], w2v = wk[ky * 3 + 2];
            float a0 = r[0], a1 = r[1], a2 = r[2], a3 = r[3], a4 = r[4], a5 = r[5];
            s0 += a0 * w0 + a1 * w1v + a2 * w2v;
            s1 += a1 * w0 + a2 * w1v + a3 * w2v;
            s2 += a2 * w0 + a3 * w1v + a4 * w2v;
            s3 += a3 * w0 + a4 * w1v + a5 * w2v;
        }
    }
    float4 v;
    v.x = fmaxf(s0, 0.f); v.y = fmaxf(s1, 0.f);
    v.z = fmaxf(s2, 0.f); v.w = fmaxf(s3, 0.f);
    *(float4*)&conv2[(t * 32 + oc) * C2_PLANE + oy * 44 + ox0] = v;
}

// Second 2x2 maxpool at sub-parity (p1,p2) -> 32 classes.
__global__ void k_pool2(const float* __restrict__ conv2, float* __restrict__ pool2) {
    int idx = blockIdx.x * 256 + threadIdx.x;     // < 495616
    int ex = idx % 22;
    int t  = idx / 22;
    int ey = t % 22;  t /= 22;
    int ch = t % 32;  t /= 32;                    // t = cls5
    int p2 = t & 1, p1 = (t >> 1) & 1;
    int cls3 = t >> 2;
    const float* c2 = conv2 + (cls3 * 32 + ch) * C2_PLANE;
    int r0 = 2 * ey + p1, r1 = r0 + 1; if (r0 > 43) r0 = 43; if (r1 > 43) r1 = 43;
    int c0 = 2 * ex + p2, c1 = c0 + 1; if (c0 > 43) c0 = 43; if (c1 > 43) c1 = 43;
    float v = fmaxf(fmaxf(c2[r0 * 44 + c0], c2[r0 * 44 + c1]),
                    fmaxf(c2[r1 * 44 + c0], c2[r1 * 44 + c1]));
    pool2[idx] = v;
}

// Fused MFMA GEMM, barrier-free main loop.
// Staging is crop-minor (scrop = tid&31): a gather instruction's lanes are 32
// consecutive crops = 4 parity classes x 8 consecutive plane columns -> coalesced.
__global__ __launch_bounds__(512) void k_fc(const float* __restrict__ pool2,
                                            const unsigned short* __restrict__ wB,
                                            const float* __restrict__ fc1_b,
                                            const float* __restrict__ fc2_w,
                                            const float* __restrict__ fc2_b,
                                            float* __restrict__ out) {
    __shared__ __align__(16) union ShMem {
        unsigned short a[32][1162];   // stride 581 dwords (odd) -> conflict-free-ish
        float h[32][132];             // epilogue overlay
    } sh;

    int tid = threadIdx.x;
    int m0  = blockIdx.x * 32;

    // ---- Stage A: thread = (kseg = tid>>5 in [0,16), scrop = tid&31)
    int scrop = tid & 31, kseg = tid >> 5;
    int cid = m0 + scrop;
    bool avalid = cid < NCROPS;
    int cidc = avalid ? cid : NCROPS - 1;
    int img = cidc / 4225;
    int rem = cidc - img * 4225;
    int i = rem / 65, j = rem - i * 65;
    int o1 = i & 1, p1 = (i >> 1) & 1, c = i >> 2;
    int o2 = j & 1, p2 = (j >> 1) & 1, d = j >> 2;
    int cls5 = (((img * 2 + o1) * 2 + o2) * 2 + p1) * 2 + p2;
    const float* pbase = pool2 + cls5 * 32 * P2_PLANE + c * 22 + d + (2 * kseg) * P2_PLANE;

    {
        unsigned int v[36];
        #pragma unroll
        for (int cc = 0; cc < 2; ++cc) {
            const float* p = pbase + cc * P2_PLANE;
            #pragma unroll
            for (int mm = 0; mm < 6; ++mm)
                #pragma unroll
                for (int e = 0; e < 3; ++e) {
                    float x0 = p[mm * 22 + 2 * e];
                    float x1 = p[mm * 22 + 2 * e + 1];
                    v[cc * 18 + mm * 3 + e] = f2bf(x0) | (f2bf(x1) << 16);
                }
        }
        uint4* dst = (uint4*)&sh.a[scrop][kseg * 72];
        #pragma unroll
        for (int q = 0; q < 9; ++q) {
            uint4 w; w.x = v[q*4]; w.y = v[q*4+1]; w.z = v[q*4+2]; w.w = v[q*4+3];
            dst[q] = w;
        }
    }

    // ---- Main loop: wave wid covers N-cols [wid*16, wid*16+16)
    int lane = tid & 63, wid = tid >> 6;
    int lm = lane & 15, lg = lane >> 4;

    const unsigned short* bp  = wB + (wid * 16 + lm) * 1152 + lg * 8;
    const unsigned short* a0p = &sh.a[lm][lg * 8];
    const unsigned short* a1p = &sh.a[16 + lm][lg * 8];

    f32x4 acc0 = {0.f, 0.f, 0.f, 0.f};
    f32x4 acc1 = {0.f, 0.f, 0.f, 0.f};

    __syncthreads();

    #pragma unroll 4
    for (int ki = 0; ki < 36; ++ki) {
        bf16x8 av0 = *(const bf16x8*)(a0p + ki * 32);
        bf16x8 av1 = *(const bf16x8*)(a1p + ki * 32);
        bf16x8 bv  = *(const bf16x8*)(bp + ki * 32);
        acc0 = __builtin_amdgcn_mfma_f32_16x16x32_bf16(av0, bv, acc0, 0, 0, 0);
        acc1 = __builtin_amdgcn_mfma_f32_16x16x32_bf16(av1, bv, acc1, 0, 0, 0);
    }

    // ---- Epilogue: bias+ReLU into H overlay (C/D: col=lm, row=lg*4+r)
    __syncthreads();   // all A reads done before overlay write
    float bias = fc1_b[wid * 16 + lm];
    #pragma unroll
    for (int r = 0; r < 4; ++r) {
        sh.h[lg * 4 + r][wid * 16 + lm]      = fmaxf(acc0[r] + bias, 0.f);
        sh.h[16 + lg * 4 + r][wid * 16 + lm] = fmaxf(acc1[r] + bias, 0.f);
    }
    __syncthreads();

    // ---- FC2: 16 threads per crop, 8 elems each, shuffle-reduce, sigmoid, scatter
    int crop_l = tid >> 4, part = tid & 15;
    const float* hh = sh.h[crop_l];
    float s = 0.f;
    #pragma unroll
    for (int u = 0; u < 8; ++u) s += hh[part * 8 + u] * fc2_w[part * 8 + u];
    s += __shfl_down(s, 8);
    s += __shfl_down(s, 4);
    s += __shfl_down(s, 2);
    s += __shfl_down(s, 1);
    if (part == 0) {
        int cid2 = m0 + crop_l;
        if (cid2 < NCROPS) {
            int img2 = cid2 / 4225;
            int rem2 = cid2 - img2 * 4225;
            int i2 = rem2 / 65, j2 = rem2 - i2 * 65;
            float q = 1.f / (1.f + expf(-(s + fc2_b[0])));
            out[img2 * (HIMG * HIMG) + (16 + i2) * HIMG + (16 + j2)] = q;
        }
    }
}

extern "C" void kernel_launch(void* const* d_in, const int* in_sizes, int n_in,
                              void* d_out, int out_size, void* d_ws, size_t ws_size,
                              hipStream_t stream) {
    const float* x     = (const float*)d_in[0];
    const float* w1    = (const float*)d_in[1];
    const float* b1    = (const float*)d_in[2];
    const float* w2    = (const float*)d_in[3];
    const float* b2    = (const float*)d_in[4];
    const float* fc1_w = (const float*)d_in[5];
    const float* fc1_b = (const float*)d_in[6];
    const float* fc2_w = (const float*)d_in[7];
    const float* fc2_b = (const float*)d_in[8];
    float* out = (float*)d_out;

    float* ws    = (float*)d_ws;
    float* pool1 = ws;                         // 270848 f32
    float* conv2 = pool1 + P1_SIZE;            // 495616 f32
    float* pool2 = conv2 + C2_SIZE;            // 495616 f32
    unsigned short* wB = (unsigned short*)(pool2 + P2_SIZE);  // 147456 bf16

    k_front<<<673, 256, 0, stream>>>(x, w1, b1, pool1, fc1_w, wB, out);
    k_conv2<<<484, 256, 0, stream>>>(pool1, w2, b2, conv2);
    k_pool2<<<C2_SIZE / 256, 256, 0, stream>>>(conv2, pool2);
    k_fc<<<(NCROPS + 31) / 32, 512, 0, stream>>>(pool2, wB, fc1_b, fc2_w, fc2_b, out);
}

// Round 5
// 69.065 us; speedup vs baseline: 1.1182x; 1.1182x over previous
//
#include <hip/hip_runtime.h>
#include <math.h>

// Problem constants
#define NB 2
#define HIMG 96
#define HO 65
#define NCROPS (NB*HO*HO)   // 8450
#define NTILES 265          // ceil(8450/32)

// pool1: [cls3=(img,o1,o2)][16ch][46][46]
#define P1_PLANE (46*46)          // 2116
#define P1_SIZE (8*16*P1_PLANE)   // 270848
// conv2: [cls3][32ch][44][44]
#define C2_PLANE (44*44)          // 1936
#define C2_SIZE (8*32*C2_PLANE)   // 495616
// pool2: [cls5=(img,o1,o2,p1,p2)][32ch][22][22]
#define P2_PLANE (22*22)          // 484
#define P2_SIZE (32*32*P2_PLANE)  // 495616

typedef __attribute__((ext_vector_type(8))) short bf16x8;
typedef __attribute__((ext_vector_type(4))) float f32x4;

__device__ __forceinline__ unsigned int f2bf(float x) {
    unsigned int u = __builtin_bit_cast(unsigned int, x);
    return (u + 0x7fffu + ((u >> 16) & 1u)) >> 16;
}

// Merged front kernel:
//   blocks [0,529)   : conv1(5x5,1->16)+ReLU+2x2 maxpool at parity -> pool1
//   blocks [529,601) : cast fc1_w -> bf16 wB
//   blocks [601,673) : zero heatmap
__global__ void k_front(const float* __restrict__ x, const float* __restrict__ w1,
                        const float* __restrict__ b1, float* __restrict__ pool1,
                        const float* __restrict__ fc1_w, unsigned short* __restrict__ wB,
                        float* __restrict__ out) {
    int b = blockIdx.x, tid = threadIdx.x;
    if (b >= 529) {
        if (b < 601) {
            int t = (b - 529) * 256 + tid;            // < 18432, 8 elements each
            const float4* src = (const float4*)fc1_w + t * 2;
            float4 a = src[0], c = src[1];
            uint4 v;
            v.x = f2bf(a.x) | (f2bf(a.y) << 16);
            v.y = f2bf(a.z) | (f2bf(a.w) << 16);
            v.z = f2bf(c.x) | (f2bf(c.y) << 16);
            v.w = f2bf(c.z) | (f2bf(c.w) << 16);
            ((uint4*)wB)[t] = v;
        } else {
            out[(b - 601) * 256 + tid] = 0.f;
        }
        return;
    }
    int idx = b * 256 + tid;                          // < 135424
    int pg = idx % 23;
    int t  = idx / 23;
    int py = t % 46;  t /= 46;
    int ch = t % 16;  t /= 16;                        // t = cls3
    int o2 = t & 1, o1 = (t >> 1) & 1, img = t >> 2;
    const float* xim = x + img * (HIMG * HIMG);

    int rbase = 2 * py + o1;
    int cbase = 4 * pg + o2;
    float a[6][8];
    #pragma unroll
    for (int i = 0; i < 6; ++i) {
        int r = rbase + i; if (r > 95) r = 95;
        const float* rp = xim + r * 96;
        #pragma unroll
        for (int j = 0; j < 8; ++j) {
            int c = cbase + j; if (c > 95) c = 95;
            a[i][j] = rp[c];
        }
    }
    const float* wc = w1 + ch * 25;
    float w[25];
    #pragma unroll
    for (int u = 0; u < 25; ++u) w[u] = wc[u];
    float bias = b1[ch];

    float out0 = 0.f, out1 = 0.f;   // relu'd values >= 0
    #pragma unroll
    for (int dy = 0; dy < 2; ++dy)
        #pragma unroll
        for (int dx = 0; dx < 2; ++dx) {
            float s0 = bias, s1 = bias;
            #pragma unroll
            for (int ky = 0; ky < 5; ++ky)
                #pragma unroll
                for (int kx = 0; kx < 5; ++kx) {
                    float wv = w[ky * 5 + kx];
                    s0 += a[dy + ky][dx + kx] * wv;
                    s1 += a[dy + ky][2 + dx + kx] * wv;
                }
            out0 = fmaxf(out0, s0);
            out1 = fmaxf(out1, s1);
        }
    int base = ((t * 16 + ch) * 46 + py) * 46 + 2 * pg;
    float2 v; v.x = out0; v.y = out1;
    *(float2*)&pool1[base] = v;
}

// conv2(3x3,16->32)+ReLU; 4 outputs along x per thread, float4 store.
__global__ void k_conv2(const float* __restrict__ pool1, const float* __restrict__ w2,
                        const float* __restrict__ b2, float* __restrict__ conv2) {
    int idx = blockIdx.x * 256 + threadIdx.x;     // < 123904
    int og = idx % 11;
    int t  = idx / 11;
    int oy = t % 44;  t /= 44;
    int oc = t % 32;  t /= 32;                    // t = cls3
    int ox0 = og * 4;
    const float* p1 = pool1 + t * 16 * P1_PLANE + oy * 46 + ox0;
    const float* ww = w2 + oc * 144;
    float b = b2[oc];
    float s0 = b, s1 = b, s2 = b, s3 = b;
    for (int ic = 0; ic < 16; ++ic) {
        const float* pp = p1 + ic * P1_PLANE;
        const float* wk = ww + ic * 9;
        #pragma unroll
        for (int ky = 0; ky < 3; ++ky) {
            const float* r = pp + ky * 46;
            float w0 = wk[ky * 3], w1v = wk[ky * 3 + 1], w2v = wk[ky * 3 + 2];
            float a0 = r[0], a1 = r[1], a2 = r[2], a3 = r[3], a4 = r[4], a5 = r[5];
            s0 += a0 * w0 + a1 * w1v + a2 * w2v;
            s1 += a1 * w0 + a2 * w1v + a3 * w2v;
            s2 += a2 * w0 + a3 * w1v + a4 * w2v;
            s3 += a3 * w0 + a4 * w1v + a5 * w2v;
        }
    }
    float4 v;
    v.x = fmaxf(s0, 0.f); v.y = fmaxf(s1, 0.f);
    v.z = fmaxf(s2, 0.f); v.w = fmaxf(s3, 0.f);
    *(float4*)&conv2[(t * 32 + oc) * C2_PLANE + oy * 44 + ox0] = v;
}

// Second 2x2 maxpool at sub-parity (p1,p2) -> 32 classes.
__global__ void k_pool2(const float* __restrict__ conv2, float* __restrict__ pool2) {
    int idx = blockIdx.x * 256 + threadIdx.x;     // < 495616
    int ex = idx % 22;
    int t  = idx / 22;
    int ey = t % 22;  t /= 22;
    int ch = t % 32;  t /= 32;                    // t = cls5
    int p2 = t & 1, p1 = (t >> 1) & 1;
    int cls3 = t >> 2;
    const float* c2 = conv2 + (cls3 * 32 + ch) * C2_PLANE;
    int r0 = 2 * ey + p1, r1 = r0 + 1; if (r0 > 43) r0 = 43; if (r1 > 43) r1 = 43;
    int c0 = 2 * ex + p2, c1 = c0 + 1; if (c0 > 43) c0 = 43; if (c1 > 43) c1 = 43;
    float v = fmaxf(fmaxf(c2[r0 * 44 + c0], c2[r0 * 44 + c1]),
                    fmaxf(c2[r1 * 44 + c0], c2[r1 * 44 + c1]));
    pool2[idx] = v;
}

// Pass 1 of FC1 GEMM, K-split: block (tile, kh) computes partial
// C[tile][kh] = A[tile crops 32 x K 576] * B[kh half]^T -> Cpart (f32).
// A-half staged in LDS (37 KB -> 2 blocks/CU). Barrier-free 18-step main loop.
__global__ __launch_bounds__(512, 4) void k_fc(const float* __restrict__ pool2,
                                               const unsigned short* __restrict__ wB,
                                               float* __restrict__ Cpart) {
    __shared__ __align__(16) unsigned short sa[32][588];  // stride 588 shorts: 2-way max

    int tid  = threadIdx.x;
    int tile = blockIdx.x >> 1;
    int kh   = blockIdx.x & 1;
    int m0   = tile * 32;

    // ---- Stage A-half: thread = (scrop = tid&31, kseg = tid>>5 in [0,16))
    // loads ONE channel's 6x6 window = 36 floats (18 independent dwordx2).
    int scrop = tid & 31, kseg = tid >> 5;
    int cid = m0 + scrop;
    int cidc = cid < NCROPS ? cid : NCROPS - 1;
    int img = cidc / 4225;
    int rem = cidc - img * 4225;
    int i = rem / 65, j = rem - i * 65;
    int o1 = i & 1, p1 = (i >> 1) & 1, c = i >> 2;
    int o2 = j & 1, p2 = (j >> 1) & 1, d = j >> 2;
    int cls5 = (((img * 2 + o1) * 2 + o2) * 2 + p1) * 2 + p2;
    const float* p = pool2 + (cls5 * 32 + kh * 16 + kseg) * P2_PLANE + c * 22 + d;

    unsigned int v[18];
    #pragma unroll
    for (int mm = 0; mm < 6; ++mm)
        #pragma unroll
        for (int e = 0; e < 3; ++e) {
            float x0 = p[mm * 22 + 2 * e];
            float x1 = p[mm * 22 + 2 * e + 1];
            v[mm * 3 + e] = f2bf(x0) | (f2bf(x1) << 16);
        }
    uint2* dst = (uint2*)&sa[scrop][kseg * 36];
    #pragma unroll
    for (int q = 0; q < 9; ++q) {
        uint2 w; w.x = v[2 * q]; w.y = v[2 * q + 1];
        dst[q] = w;
    }

    // ---- Main loop: wave wid covers N-cols [wid*16, wid*16+16), 18 K-steps
    int lane = tid & 63, wid = tid >> 6;
    int lm = lane & 15, lg = lane >> 4;

    const unsigned short* bp  = wB + (wid * 16 + lm) * 1152 + kh * 576 + lg * 8;
    const unsigned short* a0p = &sa[lm][lg * 8];
    const unsigned short* a1p = &sa[16 + lm][lg * 8];

    f32x4 acc0 = {0.f, 0.f, 0.f, 0.f};
    f32x4 acc1 = {0.f, 0.f, 0.f, 0.f};

    __syncthreads();

    #pragma unroll 9
    for (int ki = 0; ki < 18; ++ki) {
        bf16x8 av0 = *(const bf16x8*)(a0p + ki * 32);
        bf16x8 av1 = *(const bf16x8*)(a1p + ki * 32);
        bf16x8 bv  = *(const bf16x8*)(bp + ki * 32);
        acc0 = __builtin_amdgcn_mfma_f32_16x16x32_bf16(av0, bv, acc0, 0, 0, 0);
        acc1 = __builtin_amdgcn_mfma_f32_16x16x32_bf16(av1, bv, acc1, 0, 0, 0);
    }

    // ---- Write partial C: [tile][kh][crop 32][n 128] f32, coalesced per 16 lanes.
    float* cp = Cpart + (unsigned)((tile * 2 + kh) * 32) * 128 + wid * 16 + lm;
    #pragma unroll
    for (int r = 0; r < 4; ++r) {
        cp[(lg * 4 + r) * 128]        = acc0[r];
        cp[(16 + lg * 4 + r) * 128]   = acc1[r];
    }
}

// Pass 2: sum the two K-half partials, bias+ReLU, FC2 dot, sigmoid, scatter.
// 16 threads per crop, 16 crops per 256-thread block.
__global__ void k_fcep(const float* __restrict__ Cpart, const float* __restrict__ fc1_b,
                       const float* __restrict__ fc2_w, const float* __restrict__ fc2_b,
                       float* __restrict__ out) {
    int tid = threadIdx.x;
    int cg = blockIdx.x * 16 + (tid >> 4);
    int part = tid & 15;
    bool valid = cg < NCROPS;
    int cgc = valid ? cg : NCROPS - 1;
    int tile = cgc >> 5, crop = cgc & 31;
    const float* c0 = Cpart + (unsigned)((tile * 2) * 32 + crop) * 128 + part * 8;
    const float* c1 = c0 + 32 * 128;
    float4 a0 = *(const float4*)c0,       a1 = *(const float4*)(c0 + 4);
    float4 b0 = *(const float4*)c1,       b1 = *(const float4*)(c1 + 4);
    float4 fb0 = *(const float4*)&fc1_b[part * 8], fb1 = *(const float4*)&fc1_b[part * 8 + 4];
    float4 w0 = *(const float4*)&fc2_w[part * 8],  w1 = *(const float4*)&fc2_w[part * 8 + 4];
    float s = 0.f;
    s += fmaxf(a0.x + b0.x + fb0.x, 0.f) * w0.x;
    s += fmaxf(a0.y + b0.y + fb0.y, 0.f) * w0.y;
    s += fmaxf(a0.z + b0.z + fb0.z, 0.f) * w0.z;
    s += fmaxf(a0.w + b0.w + fb0.w, 0.f) * w0.w;
    s += fmaxf(a1.x + b1.x + fb1.x, 0.f) * w1.x;
    s += fmaxf(a1.y + b1.y + fb1.y, 0.f) * w1.y;
    s += fmaxf(a1.z + b1.z + fb1.z, 0.f) * w1.z;
    s += fmaxf(a1.w + b1.w + fb1.w, 0.f) * w1.w;
    s += __shfl_down(s, 8);
    s += __shfl_down(s, 4);
    s += __shfl_down(s, 2);
    s += __shfl_down(s, 1);
    if (part == 0 && valid) {
        int img = cg / 4225;
        int rem = cg - img * 4225;
        int i = rem / 65, j = rem - i * 65;
        float q = 1.f / (1.f + expf(-(s + fc2_b[0])));
        out[img * (HIMG * HIMG) + (16 + i) * HIMG + (16 + j)] = q;
    }
}

extern "C" void kernel_launch(void* const* d_in, const int* in_sizes, int n_in,
                              void* d_out, int out_size, void* d_ws, size_t ws_size,
                              hipStream_t stream) {
    const float* x     = (const float*)d_in[0];
    const float* w1    = (const float*)d_in[1];
    const float* b1    = (const float*)d_in[2];
    const float* w2    = (const float*)d_in[3];
    const float* b2    = (const float*)d_in[4];
    const float* fc1_w = (const float*)d_in[5];
    const float* fc1_b = (const float*)d_in[6];
    const float* fc2_w = (const float*)d_in[7];
    const float* fc2_b = (const float*)d_in[8];
    float* out = (float*)d_out;

    float* ws    = (float*)d_ws;
    float* pool1 = ws;                         // 270848 f32
    float* conv2 = pool1 + P1_SIZE;            // 495616 f32
    float* pool2 = conv2 + C2_SIZE;            // 495616 f32
    unsigned short* wB = (unsigned short*)(pool2 + P2_SIZE);  // 147456 bf16
    float* Cpart = (float*)(wB + 128 * 1152);  // 265*2*32*128 = 2170880 f32

    k_front<<<673, 256, 0, stream>>>(x, w1, b1, pool1, fc1_w, wB, out);
    k_conv2<<<484, 256, 0, stream>>>(pool1, w2, b2, conv2);
    k_pool2<<<C2_SIZE / 256, 256, 0, stream>>>(conv2, pool2);
    k_fc<<<NTILES * 2, 512, 0, stream>>>(pool2, wB, Cpart);
    k_fcep<<<529, 256, 0, stream>>>(Cpart, fc1_b, fc2_w, fc2_b, out);
}